// Round 7
// baseline (88.339 us; speedup 1.0000x reference)
//
#include <hip/hip_runtime.h>

#define NPTS 4096      // points per cloud
#define NB   4         // batch
#define KP   512       // keypoints
#define HUBER_C 0.01f
#define BT     256                 // threads per main block
#define QCHUNK 128                 // queries per gal block
#define NQC (NPTS / QCHUNK)        // 32
#define GAL_BLOCKS (2 * NB * NQC)  // 256
#define NPK (NPTS / 2)             // 2048 o-pair packs
#define QL  8                      // query lanes (per o-group)
#define NOG (BT / QL)              // 32 o-groups
#define PKG (NPK / NOG)            // 64 packs per group
#define QPT (QCHUNK / QL)          // 16 queries per thread
#define LDA_STRIDE (PKG + 1)       // 65: +16B per group -> 4-bank phase shift

typedef float v2f __attribute__((ext_vector_type(2)));

// Tuning log (MI355X):
//   R9:  __threadfence() per block -> 155.3. LESSON: threadfence on
//     gfx950 = buffer_wbl2/inv; serialized the chip.
//   R10: fences removed -> 122.1, main 53.7us (measured). 2M atomicMin
//     stream was the cost. NON-MAIN WINDOW = 122.1-53.7 = 68us (harness
//     268MB fills + init + gaps) -- calibration constant.
//   R11: block-local scan, 1 atomicAdd/block -> 95.0 (main ~27us,
//     LDS-issue bound: 2.1M ds_read_b128 at 1 query/thread).
//   R12: QPT=8 (DS/8) -> 85.2, main ~17us. [best]
//   R13: QPT=16 + BT=512 + launch_bounds(512,2) -> 86.6 FAILED:
//     (a) VGPR cap 128 vs ~125 live = spills in hot loop;
//     (b) shfl epilogue = ds_bpermute: +48 DS ops/thread vs 64-read scan.
//   R14 (this): QPT=16 at BT=256, NO vgpr cap, qw[] removed from regs
//     (combiner adds qlds4[q].w once at the end; min commutes with
//     +const) -> ~109 VGPR, 2 waves/SIMD possible (LDS 71KB, 2 blk/CU).
//     min3 pack-pairing (2.0 inst/dist). DS 512/CU ~2.6us, VALU ~3.4us.

// ---------------- helpers ----------------

__device__ inline float huber_f(float x) {
    return (x < HUBER_C) ? 0.5f * x * x
                         : fmaf(HUBER_C, x, -0.5f * HUBER_C * HUBER_C);
}

__device__ inline v2f splat2(float s) { v2f r; r.x = s; r.y = s; return r; }

// ---------------- kernels ----------------

__global__ void init_kernel(float* __restrict__ out) {
    if (threadIdx.x < 2) out[threadIdx.x] = 0.0f;
}

// Fused: [0,GAL_BLOCKS) gal; then knn; then kp.
// Every block ends with one atomicAdd into out[0] or out[1].
__global__ __launch_bounds__(BT) void main_kernel(
    const float* __restrict__ srcT, const float* __restrict__ tgtT,
    const float* __restrict__ skp, const float* __restrict__ tkp,
    const float* __restrict__ R, const float* __restrict__ T,
    const float* __restrict__ aknn, const float* __restrict__ bknn,
    const int* __restrict__ kptr, float* __restrict__ out,
    int knn_blocks, int knn_quads)
{
    __shared__ float4 lds_a[NOG * LDA_STRIDE];  // {x0,x1,y0,y1} per o-pair
    __shared__ float4 lds_b[NOG * LDA_STRIDE];  // {z0,z1,w0,w1} per o-pair
    __shared__ float4 qlds4[QCHUNK];            // {-2x,-2y,-2z,|q|^2}
    __shared__ float pm[BT / 64][QCHUNK + 4];   // per-wave partial mins
    __shared__ float red[BT / 64];

    const int bid = blockIdx.x;
    const int tid = threadIdx.x;
    float contrib = 0.0f;
    float* target;

    if (bid < GAL_BLOCKS) {
        // ---- global-align: 128 queries/block, 32-way o-split ----
        const int qc  = bid & (NQC - 1);
        const int b   = (bid >> 5) & 3;
        const int dir = bid >> 7;             // 0: queries=src, 1: queries=tgt
        const float* qb = (dir ? tgtT : srcT) + b * 3 * NPTS;
        const float* ob = (dir ? srcT : tgtT) + b * 3 * NPTS;

        // stage whole other-cloud into LDS, pair-packed, group-padded
        #pragma unroll
        for (int k = 0; k < NPK / BT; ++k) {           // 8 iters
            int idx = tid + k * BT;
            int j = 2 * idx;
            float2 X = *(const float2*)(ob + j);
            float2 Y = *(const float2*)(ob + NPTS + j);
            float2 Z = *(const float2*)(ob + 2 * NPTS + j);
            float w0 = fmaf(X.x, X.x, fmaf(Y.x, Y.x, Z.x * Z.x));
            float w1 = fmaf(X.y, X.y, fmaf(Y.y, Y.y, Z.y * Z.y));
            int li = idx + (idx >> 6);                 // PKG=64 group pad
            lds_a[li] = make_float4(X.x, X.y, Y.x, Y.y);
            lds_b[li] = make_float4(Z.x, Z.y, w0, w1);
        }
        // stage this block's 128 queries (pre-negated-doubled + norm)
        if (tid < QCHUNK) {
            int q = qc * QCHUNK + tid;
            float x = qb[q], y = qb[NPTS + q], z = qb[2 * NPTS + q];
            qlds4[tid] = make_float4(-2.0f * x, -2.0f * y, -2.0f * z,
                                     fmaf(x, x, fmaf(y, y, z * z)));
        }
        __syncthreads();

        // 16 queries per thread in registers (no qw: added at combiner)
        const int ql0 = tid & (QL - 1);
        const int og  = tid >> 3;                      // [0, 32)
        float ax[QPT], ay[QPT], az[QPT];
        v2f mm[QPT];
        #pragma unroll
        for (int j2 = 0; j2 < QPT; ++j2) {
            float4 Q = qlds4[ql0 + QL * j2];
            ax[j2] = Q.x; ay[j2] = Q.y; az[j2] = Q.z;
            mm[j2].x = 3.0e38f; mm[j2].y = 3.0e38f;
        }

        // inner scan: per 2 packs, 4 ds_read_b128 feed 16q x 4o = 64 dists
        const float4* la = lds_a + og * LDA_STRIDE;
        const float4* lb = lds_b + og * LDA_STRIDE;
        auto dist2 = [&](const float4& A, const float4& B, int j2) -> v2f {
            v2f X, Y, Z, W;
            X.x = A.x; X.y = A.y; Y.x = A.z; Y.y = A.w;
            Z.x = B.x; Z.y = B.y; W.x = B.z; W.y = B.w;
            return __builtin_elementwise_fma(X, splat2(ax[j2]),
                   __builtin_elementwise_fma(Y, splat2(ay[j2]),
                   __builtin_elementwise_fma(Z, splat2(az[j2]), W)));
        };
        #pragma unroll 2
        for (int p = 0; p < PKG; p += 2) {
            float4 A0 = la[p], B0 = lb[p];
            float4 A1 = la[p + 1], B1 = lb[p + 1];
            #pragma unroll
            for (int j2 = 0; j2 < QPT; ++j2) {
                v2f t0 = dist2(A0, B0, j2);
                v2f t1 = dist2(A1, B1, j2);
                mm[j2].x = fminf(fminf(mm[j2].x, t0.x), t1.x);  // v_min3
                mm[j2].y = fminf(fminf(mm[j2].y, t0.y), t1.y);
            }
        }

        // og reduce: 8 ogs/wave live in lane bits 3..5 -> 3 shfl_xor;
        // cross-wave (4 waves) via small pm array.
        const int lane = tid & 63;
        const int w = tid >> 6;
        #pragma unroll
        for (int j2 = 0; j2 < QPT; ++j2) {
            float v = fminf(mm[j2].x, mm[j2].y);
            v = fminf(v, __shfl_xor(v, 8, 64));
            v = fminf(v, __shfl_xor(v, 16, 64));
            v = fminf(v, __shfl_xor(v, 32, 64));
            if (lane < QL) pm[w][ql0 + QL * j2] = v;
        }
        __syncthreads();

        if (tid < QCHUNK) {
            float m = fminf(fminf(pm[0][tid], pm[1][tid]),
                            fminf(pm[2][tid], pm[3][tid]));
            contrib = huber_f(m + qlds4[tid].w);   // +|q|^2 once, then huber
        }
        target = out + 1;
    } else if (bid < GAL_BLOCKS + knn_blocks) {
        // ---- knn consensus: sum((a-b)^2)/k ----
        int i = (bid - GAL_BLOCKS) * BT + tid;
        if (i < knn_quads) {
            float4 va = ((const float4*)aknn)[i];
            float4 vb = ((const float4*)bknn)[i];
            float dx = va.x - vb.x, dy = va.y - vb.y;
            float dz = va.z - vb.z, dw = va.w - vb.w;
            contrib = fmaf(dx, dx, fmaf(dy, dy, fmaf(dz, dz, dw * dw)));
        }
        contrib *= 1.0f / (float)(*kptr);
        target = out;
    } else {
        // ---- keypoints: sum((R@s + t - g)^2) ----
        int i = (bid - GAL_BLOCKS - knn_blocks) * BT + tid;   // [0, NB*KP)
        int b = i >> 9;
        int n = i & (KP - 1);
        const float* r = R + b * 9;
        const float* t = T + b * 3;
        const float* s = skp + b * 3 * KP;
        const float* g = tkp + b * 3 * KP;
        float sx = s[n], sy = s[KP + n], sz = s[2 * KP + n];
        #pragma unroll
        for (int d = 0; d < 3; ++d) {
            float v = fmaf(r[d*3+0], sx, fmaf(r[d*3+1], sy, fmaf(r[d*3+2], sz, t[d])))
                      - g[d * KP + n];
            contrib = fmaf(v, v, contrib);
        }
        target = out;
    }

    // ---- block-wide sum -> single atomicAdd ----
    float v = contrib;
    #pragma unroll
    for (int off = 32; off; off >>= 1) v += __shfl_down(v, off, 64);
    if ((tid & 63) == 0) red[tid >> 6] = v;
    __syncthreads();
    if (tid == 0) {
        float s = 0.0f;
        #pragma unroll
        for (int w2 = 0; w2 < BT / 64; ++w2) s += red[w2];
        atomicAdd(target, s);
    }
}

// ---------------- launch ----------------

extern "C" void kernel_launch(void* const* d_in, const int* in_sizes, int n_in,
                              void* d_out, int out_size, void* d_ws, size_t ws_size,
                              hipStream_t stream) {
    const float* skp  = (const float*)d_in[0];   // (B,3,KP)
    const float* tkp  = (const float*)d_in[1];   // (B,3,KP)
    const float* R    = (const float*)d_in[2];   // (B,3,3)
    const float* T    = (const float*)d_in[3];   // (B,3)
    const float* aknn = (const float*)d_in[4];   // (B,3,KP,K)
    const float* bknn = (const float*)d_in[5];   // (B,3,KP,K)
    const int*   kptr = (const int*)d_in[6];     // scalar k
    const float* srcT = (const float*)d_in[7];   // (B,3,N)
    const float* tgtT = (const float*)d_in[8];   // (B,3,N)
    float* out = (float*)d_out;

    const int knn_quads  = in_sizes[4] / 4;                   // 49152
    const int knn_blocks = (knn_quads + BT - 1) / BT;         // 192
    const int kp_blocks  = (NB * KP + BT - 1) / BT;           // 8
    const int total      = GAL_BLOCKS + knn_blocks + kp_blocks;   // 456

    init_kernel<<<1, 64, 0, stream>>>(out);
    main_kernel<<<total, BT, 0, stream>>>(
        srcT, tgtT, skp, tkp, R, T, aknn, bknn, kptr, out,
        knn_blocks, knn_quads);
}

// Round 8
// 87.349 us; speedup vs baseline: 1.0113x; 1.0113x over previous
//
#include <hip/hip_runtime.h>

#define NPTS 4096      // points per cloud
#define NB   4         // batch
#define KP   512       // keypoints
#define HUBER_C 0.01f
#define QCHUNK 128                 // queries per gal block
#define NQC (NPTS / QCHUNK)        // 32
#define GAL_BLOCKS (2 * NB * NQC)  // 256
#define NPK (NPTS / 2)             // 2048 o-pair packs
#define NOG 16                     // o-groups per block (16 threads each)
#define PKG (NPK / NOG)            // 128 packs per group
#define QPT 8                      // queries per thread
#define LDA_STRIDE (PKG + 1)       // +16B/group: 4-bank phase shift -> no conflict
#define PMIN_STRIDE (QCHUNK + 4)   // same trick for the partial-min array

typedef float v2f __attribute__((ext_vector_type(2)));

// Tuning log (MI355X):
//   R9:  __threadfence() per block -> 155.3. LESSON: threadfence on
//     gfx950 = buffer_wbl2/inv (L2 writeback/inv); ~9K of them
//     serialized the memory system (main 93us, VALUBusy 9%).
//   R10: fences removed -> 122.1, main 53.7us (measured). The 2M
//     device-scope atomicMin stream was the cost (WRITE 8.4MB at
//     ~200GB/s effective RMW throughput). NON-MAIN WINDOW = 122.1-53.7
//     = ~68us: harness 2x268MB ws-poison fills @84% HBM peak + init +
//     launch gaps. This window is FIXED and untouchable from the .cpp
//     (fills happen even though this kernel never touches d_ws).
//   R11: block-local full scan, register min, 1 atomicAdd/block -> 95.0
//     (main ~27us: LDS-issue bound, 2.1M ds_read_b128, 1 query/thread).
//   R12: QPT=8, 8x DS amortization -> 85.2 [BEST, this source].
//   R13: QPT=16 + BT=512 + launch_bounds(,2): 86.6 FAILED (VGPR cap 128
//     vs ~125 live = hot-loop spills; shfl epilogue = ds_bpermute on the
//     DS pipe, +75% DS traffic).
//   R14: QPT=16 + BT=256, no cap, qw deferred: 88.3 FAILED. QPT=16
//     theory falsified twice independently: ~80 VGPR of q-state +
//     4 in-flight packs starves the scheduler; DS-halving never shows.
//   R15: REVERT to R12 exactly. Practical floor: controllable slice
//     ~15us of the ~85us window; both grounded theories for the
//     remaining ~8us upside regressed. Session floor ~= 85us.

// ---------------- helpers ----------------

__device__ inline float huber_f(float x) {
    return (x < HUBER_C) ? 0.5f * x * x
                         : fmaf(HUBER_C, x, -0.5f * HUBER_C * HUBER_C);
}

__device__ inline v2f splat2(float s) { v2f r; r.x = s; r.y = s; return r; }

// ---------------- kernels ----------------

__global__ void init_kernel(float* __restrict__ out) {
    if (threadIdx.x < 2) out[threadIdx.x] = 0.0f;
}

// Fused: [0,GAL_BLOCKS) gal; then knn; then kp.
// Every block ends with one atomicAdd into out[0] or out[1].
__global__ __launch_bounds__(256) void main_kernel(
    const float* __restrict__ srcT, const float* __restrict__ tgtT,
    const float* __restrict__ skp, const float* __restrict__ tkp,
    const float* __restrict__ R, const float* __restrict__ T,
    const float* __restrict__ aknn, const float* __restrict__ bknn,
    const int* __restrict__ kptr, float* __restrict__ out,
    int knn_blocks, int knn_quads)
{
    __shared__ float4 lds_a[NOG * LDA_STRIDE];   // {x0,x1,y0,y1} per o-pair
    __shared__ float4 lds_b[NOG * LDA_STRIDE];   // {z0,z1,w0,w1} per o-pair
    __shared__ float pminl[NOG * PMIN_STRIDE];   // per-group partial mins (+qw)
    __shared__ float red[4];

    const int bid = blockIdx.x;
    const int tid = threadIdx.x;
    float contrib = 0.0f;
    float* target;

    if (bid < GAL_BLOCKS) {
        // ---- global-align: 128 queries/block, 16-way o-split ----
        const int qc  = bid & (NQC - 1);
        const int b   = (bid >> 5) & 3;
        const int dir = bid >> 7;             // 0: queries=src, 1: queries=tgt
        const float* qb = (dir ? tgtT : srcT) + b * 3 * NPTS;
        const float* ob = (dir ? srcT : tgtT) + b * 3 * NPTS;

        // stage whole other-cloud into LDS, pair-packed, group-padded
        #pragma unroll
        for (int k = 0; k < NPK / 256; ++k) {          // 8 iters
            int idx = tid + k * 256;
            int j = 2 * idx;
            float2 X = *(const float2*)(ob + j);
            float2 Y = *(const float2*)(ob + NPTS + j);
            float2 Z = *(const float2*)(ob + 2 * NPTS + j);
            float w0 = fmaf(X.x, X.x, fmaf(Y.x, Y.x, Z.x * Z.x));
            float w1 = fmaf(X.y, X.y, fmaf(Y.y, Y.y, Z.y * Z.y));
            int li = idx + (idx >> 7);                 // group-padded index
            lds_a[li] = make_float4(X.x, X.y, Y.x, Y.y);
            lds_b[li] = make_float4(Z.x, Z.y, w0, w1);
        }

        // 8 queries per thread in registers (threads t and t^16.. share
        // queries, scan different o-groups)
        const int ql0 = tid & 15;
        const int og  = tid >> 4;
        float ax[QPT], ay[QPT], az[QPT], qw[QPT];
        v2f mm[QPT];
        #pragma unroll
        for (int j = 0; j < QPT; ++j) {
            int q = qc * QCHUNK + ql0 + 16 * j;
            float x = qb[q], y = qb[NPTS + q], z = qb[2 * NPTS + q];
            ax[j] = -2.0f * x; ay[j] = -2.0f * y; az[j] = -2.0f * z;
            qw[j] = fmaf(x, x, fmaf(y, y, z * z));
            mm[j].x = 3.0e38f; mm[j].y = 3.0e38f;
        }
        __syncthreads();

        // inner scan: per pack, 2 ds_read_b128 feed 8q x 2o = 16 dists
        const float4* la = lds_a + og * LDA_STRIDE;
        const float4* lb = lds_b + og * LDA_STRIDE;
        #pragma unroll 4
        for (int p = 0; p < PKG; ++p) {
            float4 A = la[p], B = lb[p];
            v2f X, Y, Z, W;
            X.x = A.x; X.y = A.y; Y.x = A.z; Y.y = A.w;
            Z.x = B.x; Z.y = B.y; W.x = B.z; W.y = B.w;
            #pragma unroll
            for (int j = 0; j < QPT; ++j) {
                v2f t = __builtin_elementwise_fma(X, splat2(ax[j]),
                        __builtin_elementwise_fma(Y, splat2(ay[j]),
                        __builtin_elementwise_fma(Z, splat2(az[j]), W)));
                mm[j] = __builtin_elementwise_min(mm[j], t);
            }
        }

        // partial min (+qw: exact, min commutes with constant add)
        #pragma unroll
        for (int j = 0; j < QPT; ++j)
            pminl[og * PMIN_STRIDE + ql0 + 16 * j] =
                fminf(mm[j].x, mm[j].y) + qw[j];
        __syncthreads();

        if (tid < QCHUNK) {
            float m = 3.0e38f;
            #pragma unroll
            for (int g = 0; g < NOG; ++g)
                m = fminf(m, pminl[g * PMIN_STRIDE + tid]);
            contrib = huber_f(m);
        }
        target = out + 1;
    } else if (bid < GAL_BLOCKS + knn_blocks) {
        // ---- knn consensus: sum((a-b)^2)/k ----
        int i = (bid - GAL_BLOCKS) * 256 + tid;
        if (i < knn_quads) {
            float4 va = ((const float4*)aknn)[i];
            float4 vb = ((const float4*)bknn)[i];
            float dx = va.x - vb.x, dy = va.y - vb.y;
            float dz = va.z - vb.z, dw = va.w - vb.w;
            contrib = fmaf(dx, dx, fmaf(dy, dy, fmaf(dz, dz, dw * dw)));
        }
        contrib *= 1.0f / (float)(*kptr);
        target = out;
    } else {
        // ---- keypoints: sum((R@s + t - g)^2) ----
        int i = (bid - GAL_BLOCKS - knn_blocks) * 256 + tid;   // [0, NB*KP)
        int b = i >> 9;
        int n = i & (KP - 1);
        const float* r = R + b * 9;
        const float* t = T + b * 3;
        const float* s = skp + b * 3 * KP;
        const float* g = tkp + b * 3 * KP;
        float sx = s[n], sy = s[KP + n], sz = s[2 * KP + n];
        #pragma unroll
        for (int d = 0; d < 3; ++d) {
            float v = fmaf(r[d*3+0], sx, fmaf(r[d*3+1], sy, fmaf(r[d*3+2], sz, t[d])))
                      - g[d * KP + n];
            contrib = fmaf(v, v, contrib);
        }
        target = out;
    }

    // ---- block-wide sum -> single atomicAdd ----
    float v = contrib;
    #pragma unroll
    for (int off = 32; off; off >>= 1) v += __shfl_down(v, off, 64);
    if ((tid & 63) == 0) red[tid >> 6] = v;
    __syncthreads();
    if (tid == 0)
        atomicAdd(target, red[0] + red[1] + red[2] + red[3]);
}

// ---------------- launch ----------------

extern "C" void kernel_launch(void* const* d_in, const int* in_sizes, int n_in,
                              void* d_out, int out_size, void* d_ws, size_t ws_size,
                              hipStream_t stream) {
    const float* skp  = (const float*)d_in[0];   // (B,3,KP)
    const float* tkp  = (const float*)d_in[1];   // (B,3,KP)
    const float* R    = (const float*)d_in[2];   // (B,3,3)
    const float* T    = (const float*)d_in[3];   // (B,3)
    const float* aknn = (const float*)d_in[4];   // (B,3,KP,K)
    const float* bknn = (const float*)d_in[5];   // (B,3,KP,K)
    const int*   kptr = (const int*)d_in[6];     // scalar k
    const float* srcT = (const float*)d_in[7];   // (B,3,N)
    const float* tgtT = (const float*)d_in[8];   // (B,3,N)
    float* out = (float*)d_out;

    const int knn_quads  = in_sizes[4] / 4;                 // 49152
    const int knn_blocks = (knn_quads + 255) / 256;         // 192
    const int kp_blocks  = (NB * KP + 255) / 256;           // 8
    const int total      = GAL_BLOCKS + knn_blocks + kp_blocks;   // 456

    init_kernel<<<1, 64, 0, stream>>>(out);
    main_kernel<<<total, 256, 0, stream>>>(
        srcT, tgtT, skp, tkp, R, T, aknn, bknn, kptr, out,
        knn_blocks, knn_quads);
}